// Round 1
// baseline (84.489 us; speedup 1.0000x reference)
//
#include <hip/hip_runtime.h>
#include <hip/hip_bf16.h>

#define BDIM 16
#define HDIM 128
#define TDIM 4096
#define VSZ  65536
#define NTAB (BDIM * HDIM * 256)   // 524288 floats per table

// ---------------------------------------------------------------------------
// Kernel A: per-(b,h) complex tables over the two 8-bit halves.
//   A[lo] = exp(i*(r + sum_{n<8} bit_n(lo) W[n]))      (256 entries)
//   B[hi] = exp(i*(sum_{n<8} bit_n(hi) W[8+n]))        (256 entries)
// grid = B*H = 2048 blocks, 256 threads (thread = table index)
// ---------------------------------------------------------------------------
__global__ __launch_bounds__(256) void bide_tables(
    const float* __restrict__ W, const float* __restrict__ r,
    float* __restrict__ tabAre, float* __restrict__ tabAim,
    float* __restrict__ tabBre, float* __restrict__ tabBim) {
  int bh = blockIdx.x;                  // b*128 + h
  const float* Wp = W + bh * 16;        // wave-uniform -> scalar loads
  float rv = r[bh];
  int t = threadIdx.x;                  // 0..255

  float slo = rv;
  float shi = 0.f;
#pragma unroll
  for (int n = 0; n < 8; ++n) {
    float bit = (float)((t >> n) & 1);
    slo = fmaf(bit, Wp[n], slo);
    shi = fmaf(bit, Wp[8 + n], shi);
  }
  float sl, cl, sh, ch;
  __sincosf(slo, &sl, &cl);
  __sincosf(shi, &sh, &ch);
  int o = bh * 256 + t;
  tabAre[o] = cl;  tabAim[o] = sl;
  tabBre[o] = ch;  tabBim[o] = sh;
}

// ---------------------------------------------------------------------------
// Kernel B: logits[b][hi*256+lo] = sum_h Bre[h][hi]*Are[h][lo] - Bim*Aim
// Batched GEMM-like: M=N=256, K=128, 16 batches.
// Tile 64(hi) x 64(lo), 256 threads, 4x4 per thread, K-chunks of 32 in LDS.
// grid = 16 batches * 16 tiles = 256 blocks.
// ---------------------------------------------------------------------------
__global__ __launch_bounds__(256) void bide_logits(
    const float* __restrict__ tabAre, const float* __restrict__ tabAim,
    const float* __restrict__ tabBre, const float* __restrict__ tabBim,
    float* __restrict__ logits) {
  __shared__ float lAre[32][64];
  __shared__ float lAim[32][64];
  __shared__ float lBre[32][64];
  __shared__ float lBim[32][64];

  int bid = blockIdx.x;
  int b    = bid >> 4;
  int tile = bid & 15;
  int tlo = (tile & 3) * 64;
  int thi = (tile >> 2) * 64;
  int tid = threadIdx.x;
  int tx = tid & 15;    // lo direction, 4 each
  int ty = tid >> 4;    // hi direction, 4 each

  const float* Ar = tabAre + b * HDIM * 256;
  const float* Ai = tabAim + b * HDIM * 256;
  const float* Br = tabBre + b * HDIM * 256;
  const float* Bi = tabBim + b * HDIM * 256;

  float acc[4][4] = {};

  for (int kc = 0; kc < 4; ++kc) {
    // stage 32 h-rows x 64 cols of each table
#pragma unroll
    for (int i = 0; i < 8; ++i) {
      int idx = tid + i * 256;
      int row = idx >> 6, col = idx & 63;
      int g = (kc * 32 + row) * 256;
      lAre[row][col] = Ar[g + tlo + col];
      lAim[row][col] = Ai[g + tlo + col];
      lBre[row][col] = Br[g + thi + col];
      lBim[row][col] = Bi[g + thi + col];
    }
    __syncthreads();

#pragma unroll 4
    for (int h = 0; h < 32; ++h) {
      float4 ar4 = *(const float4*)(&lAre[h][tx * 4]);
      float4 ai4 = *(const float4*)(&lAim[h][tx * 4]);
      float4 br4 = *(const float4*)(&lBre[h][ty * 4]);
      float4 bi4 = *(const float4*)(&lBim[h][ty * 4]);
      float arr[4] = {ar4.x, ar4.y, ar4.z, ar4.w};
      float aii[4] = {ai4.x, ai4.y, ai4.z, ai4.w};
      float brr[4] = {br4.x, br4.y, br4.z, br4.w};
      float bii[4] = {bi4.x, bi4.y, bi4.z, bi4.w};
#pragma unroll
      for (int i = 0; i < 4; ++i)
#pragma unroll
        for (int j = 0; j < 4; ++j) {
          acc[i][j] = fmaf(brr[i], arr[j], acc[i][j]);
          acc[i][j] = fmaf(-bii[i], aii[j], acc[i][j]);
        }
    }
    __syncthreads();
  }

  float* Lb = logits + b * VSZ;
#pragma unroll
  for (int i = 0; i < 4; ++i) {
    int hi = thi + ty * 4 + i;
    float4 v = make_float4(acc[i][0], acc[i][1], acc[i][2], acc[i][3]);
    *(float4*)(&Lb[hi * 256 + tlo + tx * 4]) = v;
  }
}

// ---------------------------------------------------------------------------
// Kernel C: per-(b,chunk) partial logsumexp. grid = 16*32 = 512 blocks,
// each block reduces 2048 logits -> (max, sum exp(x - max)).
// ---------------------------------------------------------------------------
__global__ __launch_bounds__(256) void bide_lse_part(
    const float* __restrict__ logits,
    float* __restrict__ partM, float* __restrict__ partS) {
  int bid = blockIdx.x;
  int b = bid >> 5, c = bid & 31;
  const float* L = logits + b * VSZ + c * 2048;
  int tid = threadIdx.x;
  int lane = tid & 63, wid = tid >> 6;

  float v[8];
  float m = -1e30f;
#pragma unroll
  for (int i = 0; i < 8; ++i) {
    v[i] = L[tid + i * 256];
    m = fmaxf(m, v[i]);
  }
  __shared__ float wred[4];
  __shared__ float wsum[4];
#pragma unroll
  for (int off = 1; off < 64; off <<= 1) m = fmaxf(m, __shfl_xor(m, off, 64));
  if (lane == 0) wred[wid] = m;
  __syncthreads();
  float M = fmaxf(fmaxf(wred[0], wred[1]), fmaxf(wred[2], wred[3]));

  float s = 0.f;
#pragma unroll
  for (int i = 0; i < 8; ++i) s += __expf(v[i] - M);
#pragma unroll
  for (int off = 1; off < 64; off <<= 1) s += __shfl_xor(s, off, 64);
  if (lane == 0) wsum[wid] = s;
  __syncthreads();
  if (tid == 0) {
    partM[b * 32 + c] = M;
    partS[b * 32 + c] = wsum[0] + wsum[1] + wsum[2] + wsum[3];
  }
}

// ---------------------------------------------------------------------------
// Kernel D: combine 32 partials per batch -> logZ, then gather output.
// grid = B*T/256 = 256 blocks (16 per batch).
// ---------------------------------------------------------------------------
__global__ __launch_bounds__(256) void bide_out(
    const float* __restrict__ logits,
    const float* __restrict__ partM, const float* __restrict__ partS,
    const int* __restrict__ x, float* __restrict__ out) {
  int bid = blockIdx.x;
  int b = bid >> 4;
  int t0 = (bid & 15) * 256;
  int tid = threadIdx.x;

  __shared__ float s_logZ;
  if (tid < 64) {
    float m = (tid < 32) ? partM[b * 32 + tid] : -1e30f;
    float M = m;
#pragma unroll
    for (int off = 1; off < 64; off <<= 1) M = fmaxf(M, __shfl_xor(M, off, 64));
    float s = (tid < 32) ? partS[b * 32 + tid] * __expf(m - M) : 0.f;
#pragma unroll
    for (int off = 1; off < 64; off <<= 1) s += __shfl_xor(s, off, 64);
    if (tid == 0) s_logZ = M + __logf(s);
  }
  __syncthreads();
  float logZ = s_logZ;

  int t = t0 + tid;
  int vidx = x[b * TDIM + t];
  out[b * TDIM + t] = logits[b * VSZ + vidx] - logZ;
}

// ---------------------------------------------------------------------------
extern "C" void kernel_launch(void* const* d_in, const int* in_sizes, int n_in,
                              void* d_out, int out_size, void* d_ws, size_t ws_size,
                              hipStream_t stream) {
  const int*   x = (const int*)d_in[0];     // [16][4096] int32 bit patterns
  const float* W = (const float*)d_in[1];   // [16][128][16]
  const float* r = (const float*)d_in[2];   // [16][128]
  float* out = (float*)d_out;               // [16][4096]

  float* tabAre = (float*)d_ws;
  float* tabAim = tabAre + NTAB;
  float* tabBre = tabAim + NTAB;
  float* tabBim = tabBre + NTAB;
  float* logits = tabBim + NTAB;            // 16*65536 floats
  float* partM  = logits + BDIM * VSZ;      // 16*32
  float* partS  = partM + BDIM * 32;        // 16*32

  bide_tables<<<BDIM * HDIM, 256, 0, stream>>>(W, r, tabAre, tabAim, tabBre, tabBim);
  bide_logits<<<BDIM * 16, 256, 0, stream>>>(tabAre, tabAim, tabBre, tabBim, logits);
  bide_lse_part<<<BDIM * 32, 256, 0, stream>>>(logits, partM, partS);
  bide_out<<<BDIM * TDIM / 256, 256, 0, stream>>>(logits, partM, partS, x, out);
}

// Round 3
// 83.365 us; speedup vs baseline: 1.0135x; 1.0135x over previous
//
#include <hip/hip_runtime.h>
#include <hip/hip_bf16.h>

#define BDIM 16
#define HDIM 128
#define TDIM 4096
#define VSZ  65536

// ---------------------------------------------------------------------------
// K1: fused table-gen + logits GEMM.
// logits[b][hi*256+lo] = sum_h ( cos(shi)*cos(r+slo) - sin(shi)*sin(r+slo) )
// where slo = <bits(lo), W[0:8]>, shi = <bits(hi), W[8:16]>.
// Tile 64(hi) x 64(lo), 512 threads, K(=h) chunks of 32 staged in LDS,
// table slices computed in-block (no global table traffic).
// grid = 16 batches * 16 tiles = 256 blocks.
// ---------------------------------------------------------------------------
__global__ __launch_bounds__(512) void bide_fused_logits(
    const float* __restrict__ W, const float* __restrict__ r,
    float* __restrict__ logits) {
  __shared__ float lAre[32][64];
  __shared__ float lAim[32][64];
  __shared__ float lBre[32][64];
  __shared__ float lBim[32][64];

  int bid = blockIdx.x;
  int b    = bid >> 4;
  int tile = bid & 15;
  int tlo = (tile & 3) * 64;
  int thi = (tile >> 2) * 64;
  int tid = threadIdx.x;
  int lane6 = tid & 63;   // table column (wave-uniform row -> scalar W loads)
  int wrow  = tid >> 6;   // 0..7
  int tx = tid & 15;      // lo direction, 4 outputs each
  int ty = tid >> 4;      // 0..31, hi direction, 2 outputs each

  const float* Wb = W + b * HDIM * 16;
  const float* rb = r + b * HDIM;

  float acc[2][4] = {};

  for (int kc = 0; kc < 4; ++kc) {
    int hbase = kc * 32;
    // ---- in-block table generation for h rows [hbase, hbase+32) ----
#pragma unroll
    for (int i = 0; i < 4; ++i) {
      int row = wrow + i * 8;          // 0..31, wave-uniform
      int h = hbase + row;
      const float* Wp = Wb + h * 16;
      // A: value = tlo + lane6, weights W[0..7], bias r  -> e^{i(r+slo)}
      int va = tlo + lane6;
      float sa = rb[h];
#pragma unroll
      for (int n = 0; n < 8; ++n)
        sa = fmaf((float)((va >> n) & 1), Wp[n], sa);
      float sina, cosa;
      __sincosf(sa, &sina, &cosa);
      lAre[row][lane6] = cosa;
      lAim[row][lane6] = sina;
      // B: value = thi + lane6, weights W[8..15] -> e^{i shi}
      int vb = thi + lane6;
      float sb = 0.f;
#pragma unroll
      for (int n = 0; n < 8; ++n)
        sb = fmaf((float)((vb >> n) & 1), Wp[8 + n], sb);
      float sinb, cosb;
      __sincosf(sb, &sinb, &cosb);
      lBre[row][lane6] = cosb;
      lBim[row][lane6] = sinb;
    }
    __syncthreads();

    // ---- main FMA loop over this h-chunk ----
#pragma unroll 4
    for (int h = 0; h < 32; ++h) {
      float4 ar = *(const float4*)&lAre[h][tx * 4];
      float4 ai = *(const float4*)&lAim[h][tx * 4];
      float2 br = *(const float2*)&lBre[h][ty * 2];
      float2 bi = *(const float2*)&lBim[h][ty * 2];
      float arr[4] = {ar.x, ar.y, ar.z, ar.w};
      float aii[4] = {ai.x, ai.y, ai.z, ai.w};
      float brr[2] = {br.x, br.y};
      float bii[2] = {bi.x, bi.y};
#pragma unroll
      for (int i2 = 0; i2 < 2; ++i2)
#pragma unroll
        for (int j = 0; j < 4; ++j) {
          acc[i2][j] = fmaf(brr[i2], arr[j], acc[i2][j]);
          acc[i2][j] = fmaf(-bii[i2], aii[j], acc[i2][j]);
        }
    }
    __syncthreads();
  }

  float* Lb = logits + b * VSZ;
#pragma unroll
  for (int i2 = 0; i2 < 2; ++i2) {
    int hi = thi + ty * 2 + i2;
    float4 v = make_float4(acc[i2][0], acc[i2][1], acc[i2][2], acc[i2][3]);
    *(float4*)&Lb[hi * 256 + tlo + tx * 4] = v;
  }
}

// ---------------------------------------------------------------------------
// K2: fused logsumexp + gather. One block per batch, 1024 threads.
// Two-pass (max, then sum-exp) over the 64K logits (L2/L3-resident re-read),
// then T=4096 gathered outputs.
// ---------------------------------------------------------------------------
__global__ __launch_bounds__(1024) void bide_lse_gather(
    const float* __restrict__ logits, const int* __restrict__ x,
    float* __restrict__ out) {
  int b = blockIdx.x;
  int tid = threadIdx.x;
  int lane = tid & 63, wid = tid >> 6;   // 16 waves
  const float4* L4 = (const float4*)(logits + b * VSZ);  // 16384 float4
  __shared__ float wred[16];
  __shared__ float s_logZ;

  // pass 1: block max
  float m = -1e30f;
#pragma unroll
  for (int i = 0; i < 16; ++i) {
    float4 v = L4[tid + i * 1024];
    m = fmaxf(fmaxf(fmaxf(m, v.x), v.y), fmaxf(v.z, v.w));
  }
#pragma unroll
  for (int off = 1; off < 64; off <<= 1) m = fmaxf(m, __shfl_xor(m, off, 64));
  if (lane == 0) wred[wid] = m;
  __syncthreads();
  float M = wred[0];
#pragma unroll
  for (int i = 1; i < 16; ++i) M = fmaxf(M, wred[i]);
  __syncthreads();

  // pass 2: sum exp(v - M)
  float s = 0.f;
#pragma unroll
  for (int i = 0; i < 16; ++i) {
    float4 v = L4[tid + i * 1024];
    s += __expf(v.x - M) + __expf(v.y - M) + __expf(v.z - M) + __expf(v.w - M);
  }
#pragma unroll
  for (int off = 1; off < 64; off <<= 1) s += __shfl_xor(s, off, 64);
  if (lane == 0) wred[wid] = s;
  __syncthreads();
  if (tid == 0) {
    float S = 0.f;
#pragma unroll
    for (int i = 0; i < 16; ++i) S += wred[i];
    s_logZ = M + __logf(S);
  }
  __syncthreads();
  float logZ = s_logZ;

  // gather
  const float* Lb = logits + b * VSZ;
  const int* xb = x + b * TDIM;
  float* ob = out + b * TDIM;
#pragma unroll
  for (int i = 0; i < 4; ++i) {
    int t = tid + i * 1024;
    ob[t] = Lb[xb[t]] - logZ;
  }
}

// ---------------------------------------------------------------------------
extern "C" void kernel_launch(void* const* d_in, const int* in_sizes, int n_in,
                              void* d_out, int out_size, void* d_ws, size_t ws_size,
                              hipStream_t stream) {
  const int*   x = (const int*)d_in[0];     // [16][4096] int32 bit patterns
  const float* W = (const float*)d_in[1];   // [16][128][16]
  const float* r = (const float*)d_in[2];   // [16][128]
  float* out = (float*)d_out;               // [16][4096] fp32

  float* logits = (float*)d_ws;             // 16*65536 floats = 4 MB

  bide_fused_logits<<<BDIM * 16, 512, 0, stream>>>(W, r, logits);
  bide_lse_gather<<<BDIM, 1024, 0, stream>>>(logits, x, out);
}

// Round 4
// 78.466 us; speedup vs baseline: 1.0768x; 1.0624x over previous
//
#include <hip/hip_runtime.h>
#include <hip/hip_bf16.h>

#define BDIM 16
#define HDIM 128
#define TDIM 4096
#define VSZ  65536

// ---------------------------------------------------------------------------
// K1: fused table-gen + logits GEMM.
// logits[b][hi*256+lo] = sum_h ( cos(shi)*cos(r+slo) - sin(shi)*sin(r+slo) )
// slo = <bits(lo), W[0:8]>, shi = <bits(hi), W[8:16]>.
// Tile 64(hi) x 64(lo), 512 threads. h (=K dim, 128) is SPLIT across the two
// half-blocks: each half accumulates 64 h's into a 4x4 register tile, halves
// are summed through LDS at the end. Tables computed in-block (no global
// table traffic). K-chunks of 32 h staged in 32KB LDS.
// grid = 16 batches * 16 tiles = 256 blocks (1 per CU).
// ---------------------------------------------------------------------------
__global__ __launch_bounds__(512) void bide_fused_logits(
    const float* __restrict__ W, const float* __restrict__ r,
    float* __restrict__ logits) {
  // layout: Are[32][64] | Aim[32][64] | Bre[32][64] | Bim[32][64]
  __shared__ float smem[4 * 32 * 64];   // 32 KB

  int bid = blockIdx.x;
  int b    = bid >> 4;
  int tile = bid & 15;
  int tlo = (tile & 3) * 64;
  int thi = (tile >> 2) * 64;
  int tid = threadIdx.x;
  int lane6 = tid & 63;     // staging column
  int wrow  = tid >> 6;     // 0..7 staging row base
  int half  = tid >> 8;     // 0/1: which h-half this thread accumulates
  int t  = tid & 255;
  int tx = t & 15;          // lo/4
  int ty = t >> 4;          // hi/4

  const float* Wb = W + b * HDIM * 16;
  const float* rb = r + b * HDIM;

  float acc[4][4] = {};

  for (int kc = 0; kc < 4; ++kc) {
    int hbase = kc * 32;
    __syncthreads();   // previous iteration's reads done before overwrite
    // ---- in-block table generation for h rows [hbase, hbase+32) ----
#pragma unroll
    for (int i = 0; i < 4; ++i) {
      int row = wrow + i * 8;          // 0..31, wave-uniform
      int h = hbase + row;
      const float* Wp = Wb + h * 16;
      // A: value = tlo + lane6, weights W[0..7], bias r  -> e^{i(r+slo)}
      int va = tlo + lane6;
      float sa = rb[h];
#pragma unroll
      for (int n = 0; n < 8; ++n)
        sa = fmaf((float)((va >> n) & 1), Wp[n], sa);
      float sina, cosa;
      __sincosf(sa, &sina, &cosa);
      smem[row * 64 + lane6]        = cosa;   // Are
      smem[2048 + row * 64 + lane6] = sina;   // Aim
      // B: value = thi + lane6, weights W[8..15] -> e^{i shi}
      int vb = thi + lane6;
      float sb = 0.f;
#pragma unroll
      for (int n = 0; n < 8; ++n)
        sb = fmaf((float)((vb >> n) & 1), Wp[8 + n], sb);
      float sinb, cosb;
      __sincosf(sb, &sinb, &cosb);
      smem[4096 + row * 64 + lane6] = cosb;   // Bre
      smem[6144 + row * 64 + lane6] = sinb;   // Bim
    }
    __syncthreads();

    // ---- main FMA loop: this half's 16 h-rows of the chunk ----
    int rbase = half * 16;
#pragma unroll 4
    for (int hh = 0; hh < 16; ++hh) {
      int row = rbase + hh;
      float4 ar = *(const float4*)&smem[row * 64 + tx * 4];
      float4 ai = *(const float4*)&smem[2048 + row * 64 + tx * 4];
      float4 br = *(const float4*)&smem[4096 + row * 64 + ty * 4];
      float4 bi = *(const float4*)&smem[6144 + row * 64 + ty * 4];
      float arr[4] = {ar.x, ar.y, ar.z, ar.w};
      float aii[4] = {ai.x, ai.y, ai.z, ai.w};
      float brr[4] = {br.x, br.y, br.z, br.w};
      float bii[4] = {bi.x, bi.y, bi.z, bi.w};
#pragma unroll
      for (int i = 0; i < 4; ++i)
#pragma unroll
        for (int j = 0; j < 4; ++j) {
          acc[i][j] = fmaf(brr[i], arr[j], acc[i][j]);
          acc[i][j] = fmaf(-bii[i], aii[j], acc[i][j]);
        }
    }
  }

  // ---- combine the two h-halves through LDS, half0 stores ----
  __syncthreads();
  if (half) {
#pragma unroll
    for (int i = 0; i < 4; ++i)
#pragma unroll
      for (int j = 0; j < 4; ++j)
        smem[(i * 4 + j) * 256 + t] = acc[i][j];   // [16][256], conflict-free
  }
  __syncthreads();
  if (!half) {
    float* Lb = logits + b * VSZ;
#pragma unroll
    for (int i = 0; i < 4; ++i) {
      int hi = thi + ty * 4 + i;
      float4 v;
      v.x = acc[i][0] + smem[(i * 4 + 0) * 256 + t];
      v.y = acc[i][1] + smem[(i * 4 + 1) * 256 + t];
      v.z = acc[i][2] + smem[(i * 4 + 2) * 256 + t];
      v.w = acc[i][3] + smem[(i * 4 + 3) * 256 + t];
      *(float4*)&Lb[hi * 256 + tlo + tx * 4] = v;
    }
  }
}

// ---------------------------------------------------------------------------
// K2a: per-(b,chunk) partial logsumexp. grid = 16*32 = 512 blocks,
// each block reduces 2048 logits -> (max, sum exp(x - max)).
// ---------------------------------------------------------------------------
__global__ __launch_bounds__(256) void bide_lse_part(
    const float* __restrict__ logits,
    float* __restrict__ partM, float* __restrict__ partS) {
  int bid = blockIdx.x;
  int b = bid >> 5, c = bid & 31;
  const float4* L4 = (const float4*)(logits + b * VSZ + c * 2048);  // 512 f4
  int tid = threadIdx.x;
  int lane = tid & 63, wid = tid >> 6;

  float4 v0 = L4[tid];
  float4 v1 = L4[tid + 256];
  float m = fmaxf(fmaxf(fmaxf(v0.x, v0.y), fmaxf(v0.z, v0.w)),
                  fmaxf(fmaxf(v1.x, v1.y), fmaxf(v1.z, v1.w)));
  __shared__ float wred[4];
  __shared__ float wsum[4];
#pragma unroll
  for (int off = 1; off < 64; off <<= 1) m = fmaxf(m, __shfl_xor(m, off, 64));
  if (lane == 0) wred[wid] = m;
  __syncthreads();
  float M = fmaxf(fmaxf(wred[0], wred[1]), fmaxf(wred[2], wred[3]));

  float s = __expf(v0.x - M) + __expf(v0.y - M) + __expf(v0.z - M) +
            __expf(v0.w - M) + __expf(v1.x - M) + __expf(v1.y - M) +
            __expf(v1.z - M) + __expf(v1.w - M);
#pragma unroll
  for (int off = 1; off < 64; off <<= 1) s += __shfl_xor(s, off, 64);
  if (lane == 0) wsum[wid] = s;
  __syncthreads();
  if (tid == 0) {
    partM[b * 32 + c] = M;
    partS[b * 32 + c] = wsum[0] + wsum[1] + wsum[2] + wsum[3];
  }
}

// ---------------------------------------------------------------------------
// K2b: combine 32 partials per batch -> logZ, then gather output.
// grid = B*T/256 = 256 blocks (16 per batch).
// ---------------------------------------------------------------------------
__global__ __launch_bounds__(256) void bide_out(
    const float* __restrict__ logits,
    const float* __restrict__ partM, const float* __restrict__ partS,
    const int* __restrict__ x, float* __restrict__ out) {
  int bid = blockIdx.x;
  int b = bid >> 4;
  int t0 = (bid & 15) * 256;
  int tid = threadIdx.x;

  __shared__ float s_logZ;
  if (tid < 64) {
    float m = (tid < 32) ? partM[b * 32 + tid] : -1e30f;
    float M = m;
#pragma unroll
    for (int off = 1; off < 64; off <<= 1) M = fmaxf(M, __shfl_xor(M, off, 64));
    float s = (tid < 32) ? partS[b * 32 + tid] * __expf(m - M) : 0.f;
#pragma unroll
    for (int off = 1; off < 64; off <<= 1) s += __shfl_xor(s, off, 64);
    if (tid == 0) s_logZ = M + __logf(s);
  }
  __syncthreads();
  float logZ = s_logZ;

  int t = t0 + tid;
  int vidx = x[b * TDIM + t];
  out[b * TDIM + t] = logits[b * VSZ + vidx] - logZ;
}

// ---------------------------------------------------------------------------
extern "C" void kernel_launch(void* const* d_in, const int* in_sizes, int n_in,
                              void* d_out, int out_size, void* d_ws, size_t ws_size,
                              hipStream_t stream) {
  const int*   x = (const int*)d_in[0];     // [16][4096] int32 bit patterns
  const float* W = (const float*)d_in[1];   // [16][128][16]
  const float* r = (const float*)d_in[2];   // [16][128]
  float* out = (float*)d_out;               // [16][4096] fp32

  float* logits = (float*)d_ws;             // 16*65536 floats = 4 MB
  float* partM  = logits + BDIM * VSZ;      // 16*32
  float* partS  = partM + BDIM * 32;        // 16*32

  bide_fused_logits<<<BDIM * 16, 512, 0, stream>>>(W, r, logits);
  bide_lse_part<<<BDIM * 32, 256, 0, stream>>>(logits, partM, partS);
  bide_out<<<BDIM * TDIM / 256, 256, 0, stream>>>(logits, partM, partS, x, out);
}

// Round 5
// 70.848 us; speedup vs baseline: 1.1925x; 1.1075x over previous
//
#include <hip/hip_runtime.h>
#include <hip/hip_bf16.h>

#define BDIM 16
#define HDIM 128
#define TDIM 4096
#define VSZ  65536

typedef __attribute__((ext_vector_type(8))) short bf16x8;
typedef __attribute__((ext_vector_type(4))) float f32x4;

// round-to-nearest-even fp32 -> bf16 (inputs are bounded cos/sin, no NaN)
static __device__ __forceinline__ unsigned int f2bf(float f) {
  unsigned int u = __float_as_uint(f);
  return (u + 0x7fffu + ((u >> 16) & 1u)) >> 16;
}

// ---------------------------------------------------------------------------
// K1: fused table-gen + bf16-MFMA logits GEMM + per-tile partial LSE.
// logits[b][hi*256+lo] = sum_k U[k][hi] * V[k][lo],  K = 256:
//   U[2h][hi] = cos(s_hi),  U[2h+1][hi] = -sin(s_hi),  s_hi = <bits(hi),W[8:16]>
//   V[2h][lo] = cos(r+s_lo), V[2h+1][lo] =  sin(r+s_lo), s_lo = <bits(lo),W[0:8]>
// Tile 64(hi) x 64(lo), 512 threads (8 waves), K-chunks of 64 staged in LDS
// as [row][k] bf16 pairs with XOR-swizzle (T2) for conflict-free b128 reads.
// Each wave: 16 rows x 32 cols (2 fragments), 16 MFMA total.
// After the GEMM each block reduces its own 64x64 tile to (max, sumexp).
// grid = 16 batches * 16 tiles = 256 blocks.
// ---------------------------------------------------------------------------
__global__ __launch_bounds__(512) void bide_logits_mfma(
    const float* __restrict__ W, const float* __restrict__ r,
    float* __restrict__ logits, float* __restrict__ partM,
    float* __restrict__ partS) {
  __shared__ unsigned int stg[2][64 * 32];  // [tab][row][kpair] bf16x2, 16 KB
  __shared__ float red[16];

  int bid = blockIdx.x;
  int b    = bid >> 4;
  int tile = bid & 15;
  int tlo = (tile & 3) * 64;
  int thi = (tile >> 2) * 64;
  int tid = threadIdx.x;

  // staging role: tab 0 = U (hi side, W[8..15], no bias, -sin)
  //               tab 1 = V (lo side, W[0..7], bias r, +sin)
  int tab  = tid >> 8;
  int srow = tid & 63;
  int grp  = (tid >> 6) & 3;
  int sval = (tab ? tlo : thi) + srow;   // table value whose bits we dot
  int woff = tab ? 0 : 8;

  // compute role: wave w -> rows [16*(w&3)), cols [32*(w>>2))
  int l = tid & 63;
  int w = tid >> 6;
  int rowblk = w & 3, colhalf = w >> 2;
  int r15 = l & 15, kl = l >> 4;
  int arow  = rowblk * 16 + r15;
  int brow0 = colhalf * 32 + r15;
  int brow1 = brow0 + 16;

  const float* Wb = W + b * HDIM * 16;
  const float* rb = r + b * HDIM;

  f32x4 acc0 = {0.f, 0.f, 0.f, 0.f};
  f32x4 acc1 = {0.f, 0.f, 0.f, 0.f};

  const bf16x8* U8 = (const bf16x8*)stg[0];
  const bf16x8* V8 = (const bf16x8*)stg[1];
  unsigned int* stow = stg[tab];

  for (int kc = 0; kc < 4; ++kc) {   // 4 chunks of 32 h (= 64 k)
    int hbase = kc * 32;
    __syncthreads();                 // prev chunk's frag reads done
#pragma unroll
    for (int e = 0; e < 8; ++e) {
      int hp = grp * 8 + e;          // 0..31 within chunk
      int h = hbase + hp;
      const float* Wp = Wb + h * 16 + woff;   // wave-uniform address
      float sacc = tab ? rb[h] : 0.f;
#pragma unroll
      for (int n = 0; n < 8; ++n)
        sacc = fmaf((float)((sval >> n) & 1), Wp[n], sacc);
      float sn, cs;
      __sincosf(sacc, &sn, &cs);
      if (!tab) sn = -sn;
      // k = 2*hp (cos) and 2*hp+1 (sin) packed in one u32; XOR-swizzled
      stow[srow * 32 + (hp ^ ((srow & 7) << 2))] = f2bf(cs) | (f2bf(sn) << 16);
    }
    __syncthreads();

#pragma unroll
    for (int ks = 0; ks < 2; ++ks) { // 2 k-steps of 32 per chunk
      bf16x8 a  = U8[arow  * 8 + ((ks * 4 + kl) ^ (arow  & 7))];
      bf16x8 b0 = V8[brow0 * 8 + ((ks * 4 + kl) ^ (brow0 & 7))];
      bf16x8 b1 = V8[brow1 * 8 + ((ks * 4 + kl) ^ (brow1 & 7))];
      acc0 = __builtin_amdgcn_mfma_f32_16x16x32_bf16(a, b0, acc0, 0, 0, 0);
      acc1 = __builtin_amdgcn_mfma_f32_16x16x32_bf16(a, b1, acc1, 0, 0, 0);
    }
  }

  // ---- write logits tile (C/D: col = lane&15, row = 4*(lane>>4)+reg) ----
  float* Lb = logits + b * VSZ;
  int orow = thi + rowblk * 16 + 4 * kl;
  int ocol = tlo + colhalf * 32 + r15;
#pragma unroll
  for (int q = 0; q < 4; ++q) {
    Lb[(orow + q) * 256 + ocol]      = acc0[q];
    Lb[(orow + q) * 256 + ocol + 16] = acc1[q];
  }

  // ---- per-tile partial logsumexp from registers ----
  float m = fmaxf(fmaxf(fmaxf(acc0[0], acc0[1]), fmaxf(acc0[2], acc0[3])),
                  fmaxf(fmaxf(acc1[0], acc1[1]), fmaxf(acc1[2], acc1[3])));
#pragma unroll
  for (int off = 1; off < 64; off <<= 1) m = fmaxf(m, __shfl_xor(m, off, 64));
  if (l == 0) red[w] = m;
  __syncthreads();
  float M = red[0];
#pragma unroll
  for (int i = 1; i < 8; ++i) M = fmaxf(M, red[i]);
  float s = 0.f;
#pragma unroll
  for (int q = 0; q < 4; ++q)
    s += __expf(acc0[q] - M) + __expf(acc1[q] - M);
#pragma unroll
  for (int off = 1; off < 64; off <<= 1) s += __shfl_xor(s, off, 64);
  if (l == 0) red[8 + w] = s;
  __syncthreads();
  if (tid == 0) {
    float S = 0.f;
#pragma unroll
    for (int i = 0; i < 8; ++i) S += red[8 + i];
    partM[bid] = M;
    partS[bid] = S;
  }
}

// ---------------------------------------------------------------------------
// K2: combine 16 tile-partials per batch -> logZ, then gather.
// grid = B*T/256 = 256 blocks (16 segments per batch).
// ---------------------------------------------------------------------------
__global__ __launch_bounds__(256) void bide_out(
    const float* __restrict__ logits,
    const float* __restrict__ partM, const float* __restrict__ partS,
    const int* __restrict__ x, float* __restrict__ out) {
  int bid = blockIdx.x;
  int b   = bid >> 4;
  int seg = bid & 15;
  int tid = threadIdx.x;
  __shared__ float s_logZ;
  if (tid < 64) {
    float m  = (tid < 16) ? partM[b * 16 + tid] : -1e30f;
    float sv = (tid < 16) ? partS[b * 16 + tid] : 0.f;
    float M = m;
#pragma unroll
    for (int off = 1; off < 16; off <<= 1) M = fmaxf(M, __shfl_xor(M, off, 16));
    float z = sv * __expf(m - M);
#pragma unroll
    for (int off = 1; off < 16; off <<= 1) z += __shfl_xor(z, off, 16);
    if (tid == 0) s_logZ = M + __logf(z);
  }
  __syncthreads();
  int t = seg * 256 + tid;
  int vidx = x[b * TDIM + t];
  out[b * TDIM + t] = logits[b * VSZ + vidx] - s_logZ;
}

// ---------------------------------------------------------------------------
extern "C" void kernel_launch(void* const* d_in, const int* in_sizes, int n_in,
                              void* d_out, int out_size, void* d_ws, size_t ws_size,
                              hipStream_t stream) {
  const int*   x = (const int*)d_in[0];     // [16][4096] int32 bit patterns
  const float* W = (const float*)d_in[1];   // [16][128][16]
  const float* r = (const float*)d_in[2];   // [16][128]
  float* out = (float*)d_out;               // [16][4096] fp32

  float* logits = (float*)d_ws;             // 16*65536 floats = 4 MB
  float* partM  = logits + BDIM * VSZ;      // 256
  float* partS  = partM + 256;              // 256

  bide_logits_mfma<<<BDIM * 16, 512, 0, stream>>>(W, r, logits, partM, partS);
  bide_out<<<BDIM * TDIM / 256, 256, 0, stream>>>(logits, partM, partS, x, out);
}

// Round 6
// 69.273 us; speedup vs baseline: 1.2197x; 1.0227x over previous
//
#include <hip/hip_runtime.h>
#include <hip/hip_bf16.h>

#define BDIM 16
#define HDIM 128
#define TDIM 4096
#define VSZ  65536

typedef __attribute__((ext_vector_type(8))) short bf16x8;
typedef __attribute__((ext_vector_type(4))) float f32x4;

// round-to-nearest-even fp32 -> bf16 (inputs are bounded cos/sin, no NaN)
static __device__ __forceinline__ unsigned int f2bf(float f) {
  unsigned int u = __float_as_uint(f);
  return (u + 0x7fffu + ((u >> 16) & 1u)) >> 16;
}

// ---------------------------------------------------------------------------
// K1: fused table-gen + bf16-MFMA tile GEMM + per-tile partial LSE
//     + in-LDS gather of this tile's samples (writes logit_x to out).
// logits[hi*256+lo] = sum_k U[k][hi]*V[k][lo], K=256:
//   U[2h][hi] = cos(s_hi), U[2h+1][hi] = -sin(s_hi), s_hi=<bits(hi),W[8:16]>
//   V[2h][lo] = cos(r+s_lo), V[2h+1][lo] = sin(r+s_lo), s_lo=<bits(lo),W[0:8]>
// Tile 64(hi)x64(lo), 512 threads (8 waves). No logits in global memory:
// the tile lives in LDS; each block scans x[b,:] and serves the samples
// whose pattern falls inside its tile (each v belongs to exactly one tile).
// grid = 16 batches * 16 tiles = 256 blocks (1 per CU).
// ---------------------------------------------------------------------------
__global__ __launch_bounds__(512) void bide_main(
    const float* __restrict__ W, const float* __restrict__ r,
    const int* __restrict__ x, float* __restrict__ out,
    float* __restrict__ partM, float* __restrict__ partS) {
  __shared__ unsigned int stg[2][64 * 32];  // staged U/V bf16 pairs, 16 KB
  __shared__ float ldsT[64 * 64];           // logits tile (swizzled), 16 KB
  __shared__ float red[16];

  int bid = blockIdx.x;
  int b    = bid >> 4;
  int tile = bid & 15;
  int tlo = (tile & 3) * 64;
  int thi = (tile >> 2) * 64;
  int tid = threadIdx.x;

  // staging role: tab 0 = U (hi side, W[8..15], no bias, -sin)
  //               tab 1 = V (lo side, W[0..7], bias r, +sin)
  int tab  = tid >> 8;
  int srow = tid & 63;
  int grp  = (tid >> 6) & 3;
  int sval = (tab ? tlo : thi) + srow;
  int woff = tab ? 0 : 8;
  int swz  = (srow & 7) << 2;       // u32-granularity XOR (== 16B-gran row&7)

  // compute role: wave w -> rows 16*(w&3), cols 32*(w>>2)
  int l = tid & 63;
  int w = tid >> 6;
  int rowblk = w & 3, colhalf = w >> 2;
  int r15 = l & 15, kl = l >> 4;
  int arow  = rowblk * 16 + r15;
  int brow0 = colhalf * 32 + r15;
  int brow1 = brow0 + 16;

  const float* Wb = W + b * HDIM * 16;
  const float* rb = r + b * HDIM;

  // hoist bit floats (loop-invariant per thread)
  float fb[8];
#pragma unroll
  for (int n = 0; n < 8; ++n) fb[n] = (float)((sval >> n) & 1);

  f32x4 acc0 = {0.f, 0.f, 0.f, 0.f};
  f32x4 acc1 = {0.f, 0.f, 0.f, 0.f};

  const bf16x8* U8 = (const bf16x8*)stg[0];
  const bf16x8* V8 = (const bf16x8*)stg[1];
  unsigned int* stow = stg[tab];

  for (int kc = 0; kc < 4; ++kc) {   // 4 chunks of 32 h (= 64 k)
    int hbase = kc * 32;
    __syncthreads();                 // prev chunk's frag reads done
#pragma unroll
    for (int e = 0; e < 8; e += 2) { // paired -> ds_write_b64
      int hp = grp * 8 + e;
      unsigned int uu0, uu1;
#pragma unroll
      for (int p = 0; p < 2; ++p) {
        int h = hbase + hp + p;
        const float* Wp = Wb + h * 16 + woff;   // wave-uniform address
        float sacc = tab ? rb[h] : 0.f;
#pragma unroll
        for (int n = 0; n < 8; ++n) sacc = fmaf(fb[n], Wp[n], sacc);
        float sn, cs;
        __sincosf(sacc, &sn, &cs);
        if (!tab) sn = -sn;
        unsigned int uv = f2bf(cs) | (f2bf(sn) << 16);
        if (p == 0) uu0 = uv; else uu1 = uv;
      }
      int idx = srow * 32 + (hp ^ swz);  // hp even, swz bits 2-4 -> idx even
      *(uint2*)&stow[idx] = make_uint2(uu0, uu1);
    }
    __syncthreads();

#pragma unroll
    for (int ks = 0; ks < 2; ++ks) { // 2 k-steps of 32 per chunk
      bf16x8 a  = U8[arow  * 8 + ((ks * 4 + kl) ^ (arow  & 7))];
      bf16x8 b0 = V8[brow0 * 8 + ((ks * 4 + kl) ^ (brow0 & 7))];
      bf16x8 b1 = V8[brow1 * 8 + ((ks * 4 + kl) ^ (brow1 & 7))];
      acc0 = __builtin_amdgcn_mfma_f32_16x16x32_bf16(a, b0, acc0, 0, 0, 0);
      acc1 = __builtin_amdgcn_mfma_f32_16x16x32_bf16(a, b1, acc1, 0, 0, 0);
    }
  }

  // ---- stash tile to LDS, swizzled col-major: elem(row,col) at
  //      col*64 + (row ^ ((col&7)<<3)); float4-contiguous in row ----
  {
    int c0  = colhalf * 32 + r15;
    int rb0 = rowblk * 16 + 4 * kl;
    int sw  = (c0 & 7) << 3;          // same for c0 and c0+16
    *(f32x4*)&ldsT[c0 * 64 + (rb0 ^ sw)]        = acc0;
    *(f32x4*)&ldsT[(c0 + 16) * 64 + (rb0 ^ sw)] = acc1;
  }

  // ---- per-tile partial logsumexp from registers ----
  float m = fmaxf(fmaxf(fmaxf(acc0[0], acc0[1]), fmaxf(acc0[2], acc0[3])),
                  fmaxf(fmaxf(acc1[0], acc1[1]), fmaxf(acc1[2], acc1[3])));
#pragma unroll
  for (int off = 1; off < 64; off <<= 1) m = fmaxf(m, __shfl_xor(m, off, 64));
  if (l == 0) red[w] = m;
  __syncthreads();                    // red ready; also ldsT complete
  float M = red[0];
#pragma unroll
  for (int i = 1; i < 8; ++i) M = fmaxf(M, red[i]);
  float s = 0.f;
#pragma unroll
  for (int q = 0; q < 4; ++q)
    s += __expf(acc0[q] - M) + __expf(acc1[q] - M);
#pragma unroll
  for (int off = 1; off < 64; off <<= 1) s += __shfl_xor(s, off, 64);
  if (l == 0) red[8 + w] = s;
  __syncthreads();
  if (tid == 0) {
    float S = 0.f;
#pragma unroll
    for (int i = 0; i < 8; ++i) S += red[8 + i];
    partM[bid] = M;
    partS[bid] = S;
  }

  // ---- scan x[b,:]; serve samples landing in this tile ----
  const int4* x4 = (const int4*)(x + b * TDIM);
  float* ob = out + b * TDIM;
#pragma unroll
  for (int it = 0; it < 2; ++it) {
    int4 xv = x4[tid + it * 512];
    int tbase = 4 * (tid + it * 512);
    int vv[4] = {xv.x, xv.y, xv.z, xv.w};
#pragma unroll
    for (int j = 0; j < 4; ++j) {
      int v = vv[j];
      int tl = ((v >> 14) << 2) | ((v >> 6) & 3);
      if (tl == tile) {
        int row = (v >> 8) & 63, col = v & 63;
        ob[tbase + j] = ldsT[col * 64 + (row ^ ((col & 7) << 3))];
      }
    }
  }
}

// ---------------------------------------------------------------------------
// K2: logZ from the 16 tile-partials (uniform per block), out -= logZ.
// grid = 64 blocks (4 segments x 16 batches), 256 threads, float4 each.
// ---------------------------------------------------------------------------
__global__ __launch_bounds__(256) void bide_sub(
    float* __restrict__ out, const float* __restrict__ partM,
    const float* __restrict__ partS) {
  int bid = blockIdx.x;
  int b = bid >> 2, seg = bid & 3;
  float M = -1e30f;
#pragma unroll
  for (int i = 0; i < 16; ++i) M = fmaxf(M, partM[b * 16 + i]);
  float S = 0.f;
#pragma unroll
  for (int i = 0; i < 16; ++i)
    S += partS[b * 16 + i] * __expf(partM[b * 16 + i] - M);
  float logZ = M + __logf(S);
  float4* o4 = (float4*)(out + b * TDIM + seg * 1024);
  float4 v = o4[threadIdx.x];
  v.x -= logZ; v.y -= logZ; v.z -= logZ; v.w -= logZ;
  o4[threadIdx.x] = v;
}

// ---------------------------------------------------------------------------
extern "C" void kernel_launch(void* const* d_in, const int* in_sizes, int n_in,
                              void* d_out, int out_size, void* d_ws, size_t ws_size,
                              hipStream_t stream) {
  const int*   x = (const int*)d_in[0];     // [16][4096] int32 bit patterns
  const float* W = (const float*)d_in[1];   // [16][128][16]
  const float* r = (const float*)d_in[2];   // [16][128]
  float* out = (float*)d_out;               // [16][4096] fp32

  float* partM = (float*)d_ws;              // 256 floats
  float* partS = partM + 256;               // 256 floats

  bide_main<<<BDIM * 16, 512, 0, stream>>>(W, r, x, out, partM, partS);
  bide_sub<<<64, 256, 0, stream>>>(out, partM, partS);
}